// Round 3
// baseline (557.968 us; speedup 1.0000x reference)
//
#include <hip/hip_runtime.h>

// VQ quantizer: N=65536 rows (D=64) vs K=4096 codes. d_out = FLOAT32
// [x_quantized N*D][indices N][loss 1]  (layout confirmed in round 2).
//
// Round-3: the np reference is a float32 numpy port (fp64-exact argmin failed
// => ref has f32 rounding flips). Emulate numpy f32 bit-exactly:
//   mm   : OpenBLAS sgemm inner product = sequential-k FMA  -> __fmaf_rn, d ascending
//   dist : fl( fl(sx + sc) - fl(2*mm) )                     -> __fadd_rn/__fsub_rn
//   sx,sc: numpy pairwise_sum n=64 pattern (8 strided accumulators + tree)
//   argmin: first minimum (strict <, ascending k, lex (v,idx) reduce)

#define D  64
#define BM 64   // rows per block in argmin kernel
#define KT 64   // codes per LDS tile

// numpy scalar pairwise_sum for n=64 of fl(p[i]^2): 8 strided accumulators,
// then ((r0+r1)+(r2+r3)) + ((r4+r5)+(r6+r7)). Strict f32, no contraction.
__device__ __forceinline__ float np_pairwise_sumsq_64(const float* p) {
    float r[8];
    #pragma unroll
    for (int j = 0; j < 8; ++j) r[j] = __fmul_rn(p[j], p[j]);
    #pragma unroll
    for (int i = 8; i < 64; i += 8) {
        #pragma unroll
        for (int j = 0; j < 8; ++j)
            r[j] = __fadd_rn(r[j], __fmul_rn(p[i + j], p[i + j]));
    }
    float t0 = __fadd_rn(r[0], r[1]);
    float t1 = __fadd_rn(r[2], r[3]);
    float t2 = __fadd_rn(r[4], r[5]);
    float t3 = __fadd_rn(r[6], r[7]);
    return __fadd_rn(__fadd_rn(t0, t1), __fadd_rn(t2, t3));
}

// one thread per row: out[r] = np-pairwise sum of squares of a[r][0..63]
__global__ __launch_bounds__(256) void rowsumsq_kernel(const float* __restrict__ a,
                                                       float* __restrict__ out, int nrows) {
    int r = blockIdx.x * 256 + threadIdx.x;
    if (r >= nrows) return;
    float buf[64];
    const float4* p = (const float4*)(a + (size_t)r * D);
    #pragma unroll
    for (int i = 0; i < 16; ++i) {
        float4 v = p[i];
        buf[4 * i] = v.x; buf[4 * i + 1] = v.y; buf[4 * i + 2] = v.z; buf[4 * i + 3] = v.w;
    }
    out[r] = np_pairwise_sumsq_64(buf);
}

// per-row argmin of fl(fl(sx+sc_k) - fl(2*dot(x,c_k))), dot = sequential f32 FMA.
// 256 threads, BM=64 rows/block, KT=64 codes per tile, 4x4 micro-tile/thread.
__global__ __launch_bounds__(256) void argmin_kernel(
    const float* __restrict__ x, const float* __restrict__ cb,
    const float* __restrict__ sx, const float* __restrict__ sc,
    int* __restrict__ idxbuf, int N, int K)
{
    __shared__ float xs[D][BM + 4];   // [d][row]  (+4 pad keeps 16B-aligned rows: 272B)
    __shared__ float cs[D][KT + 4];   // [d][code]
    __shared__ float redv[BM][16];
    __shared__ int   redi[BM][16];

    const int tid = threadIdx.x;
    const int n0  = blockIdx.x * BM;
    const int tx  = tid & 15, ty = tid >> 4;

    // stage x tile transposed (coalesced global read)
    #pragma unroll
    for (int j = 0; j < (BM * D) / 256; ++j) {
        int e = tid + j * 256;
        int r = e >> 6, d = e & 63;
        xs[d][r] = x[(size_t)(n0 + r) * D + d];
    }

    float sxr[4];
    #pragma unroll
    for (int r = 0; r < 4; ++r) sxr[r] = sx[n0 + ty * 4 + r];

    float bestv[4]; int besti[4];
    #pragma unroll
    for (int r = 0; r < 4; ++r) { bestv[r] = 3.4e38f; besti[r] = 0; }

    const int nt = K / KT;
    for (int t = 0; t < nt; ++t) {
        __syncthreads();   // protect cs (and xs on t==0)
        #pragma unroll
        for (int j = 0; j < (KT * D) / 256; ++j) {
            int e = tid + j * 256;
            int r = e >> 6, d = e & 63;
            cs[d][r] = cb[(size_t)(t * KT + r) * D + d];
        }
        __syncthreads();

        float acc[4][4];
        #pragma unroll
        for (int r = 0; r < 4; ++r)
            #pragma unroll
            for (int c = 0; c < 4; ++c) acc[r][c] = 0.0f;

        // d STRICTLY ascending; one sequential FMA chain per (r,c) element —
        // bit-exact emulation of the BLAS sgemm inner product.
        #pragma unroll 4
        for (int d = 0; d < D; ++d) {
            float4 xv = *(const float4*)&xs[d][ty * 4];
            float4 cv = *(const float4*)&cs[d][tx * 4];
            float xr[4] = {xv.x, xv.y, xv.z, xv.w};
            float cc[4] = {cv.x, cv.y, cv.z, cv.w};
            #pragma unroll
            for (int r = 0; r < 4; ++r)
                #pragma unroll
                for (int c = 0; c < 4; ++c)
                    acc[r][c] = __fmaf_rn(xr[r], cc[c], acc[r][c]);
        }

        // scores; k ascends (t asc, c asc) so strict '<' keeps the FIRST minimum
        #pragma unroll
        for (int c = 0; c < 4; ++c) {
            int k = t * KT + tx * 4 + c;
            float sck = sc[k];
            #pragma unroll
            for (int r = 0; r < 4; ++r) {
                float tt = __fadd_rn(sxr[r], sck);          // fl(sx + sc)
                float u  = __fmul_rn(2.0f, acc[r][c]);      // fl(2*mm), exact
                float s  = __fsub_rn(tt, u);                // fl(t - u)
                if (s < bestv[r]) { bestv[r] = s; besti[r] = k; }
            }
        }
    }

    __syncthreads();
    #pragma unroll
    for (int r = 0; r < 4; ++r) { redv[ty * 4 + r][tx] = bestv[r]; redi[ty * 4 + r][tx] = besti[r]; }
    __syncthreads();

    if (tid < BM) {
        float bv = redv[tid][0]; int bi = redi[tid][0];
        #pragma unroll
        for (int i = 1; i < 16; ++i) {
            float v = redv[tid][i]; int ii = redi[tid][i];
            // lexicographic (score, index): np.argmin first-min tie-break
            if (v < bv || (v == bv && ii < bi)) { bv = v; bi = ii; }
        }
        idxbuf[n0 + tid] = bi;
    }
}

// gather codebook row, write f32 x_quantized and f32 index, fp64 loss partials.
__global__ __launch_bounds__(256) void finalize_rows(
    const float* __restrict__ x, const float* __restrict__ cb,
    const int* __restrict__ idxbuf,
    float* __restrict__ out_q, float* __restrict__ out_i,
    double* __restrict__ partials, int N)
{
    __shared__ double wsum[4];
    int wid = threadIdx.x >> 6, lane = threadIdx.x & 63;
    int n = blockIdx.x * 4 + wid;

    int idx = idxbuf[n];
    float q  = cb[(size_t)idx * D + lane];
    float xv = x[(size_t)n * D + lane];
    out_q[(size_t)n * D + lane] = q;   // x + sg(q-x) == q in value (diff << threshold)

    double diff = (double)xv - (double)q;
    double s = diff * diff;
    #pragma unroll
    for (int off = 32; off > 0; off >>= 1) s += __shfl_down(s, off, 64);
    if (lane == 0) {
        wsum[wid] = s;
        out_i[n] = (float)idx;
    }
    __syncthreads();
    if (threadIdx.x == 0) partials[blockIdx.x] = (wsum[0] + wsum[1]) + (wsum[2] + wsum[3]);
}

// deterministic loss reduction: loss = 1.25 * sum / (N*D)
__global__ __launch_bounds__(256) void loss_kernel(const double* __restrict__ partials,
                                                   int nP, float* __restrict__ out_loss,
                                                   double invND)
{
    __shared__ double red[256];
    double s = 0.0;
    for (int i = threadIdx.x; i < nP; i += 256) s += partials[i];
    red[threadIdx.x] = s;
    __syncthreads();
    #pragma unroll
    for (int step = 128; step > 0; step >>= 1) {
        if ((int)threadIdx.x < step) red[threadIdx.x] += red[threadIdx.x + step];
        __syncthreads();
    }
    if (threadIdx.x == 0) {
        double m = red[0] * invND;
        out_loss[0] = (float)(0.25 * m + m);
    }
}

extern "C" void kernel_launch(void* const* d_in, const int* in_sizes, int n_in,
                              void* d_out, int out_size, void* d_ws, size_t ws_size,
                              hipStream_t stream)
{
    const float* x  = (const float*)d_in[0];
    const float* cb = (const float*)d_in[1];
    const int N = in_sizes[0] / D;   // 65536
    const int K = in_sizes[1] / D;   // 4096

    float* out      = (float*)d_out;
    float* out_q    = out;                      // N*D f32
    float* out_i    = out + (size_t)N * D;      // N f32
    float* out_loss = out_i + N;                // 1 f32

    char*   ws       = (char*)d_ws;
    float*  sx       = (float*)ws;                                   // N f32
    float*  sc       = (float*)(ws + (size_t)N * 4);                 // K f32
    int*    idxbuf   = (int*)  (ws + (size_t)(N + K) * 4);           // N int
    double* partials = (double*)(ws + (size_t)(N + K) * 4 + (size_t)N * 4);  // N/4 f64

    rowsumsq_kernel<<<(N + 255) / 256, 256, 0, stream>>>(x, sx, N);
    rowsumsq_kernel<<<(K + 255) / 256, 256, 0, stream>>>(cb, sc, K);
    argmin_kernel<<<N / BM, 256, 0, stream>>>(x, cb, sx, sc, idxbuf, N, K);
    finalize_rows<<<N / 4, 256, 0, stream>>>(x, cb, idxbuf, out_q, out_i, partials, N);
    loss_kernel<<<1, 256, 0, stream>>>(partials, N / 4, out_loss,
                                       1.0 / ((double)N * (double)D));
}